// Round 1
// baseline (53479.199 us; speedup 1.0000x reference)
//
#include <hip/hip_runtime.h>
#include <stdint.h>

#define BB 64
#define TT 1024
#define EE 512
#define HH 512
#define NGRP 4
#define WGS_PER_GROUP 64

typedef float v4f __attribute__((ext_vector_type(4)));
typedef short v8s __attribute__((ext_vector_type(8)));

__device__ __forceinline__ short f2bf(float f) {
    unsigned u = __float_as_uint(f);
    u += 0x7fffu + ((u >> 16) & 1u);          // RNE to bf16
    return (short)(u >> 16);
}

__device__ __forceinline__ float sigmoidf_(float x) {
    x = fminf(fmaxf(x, -30.f), 30.f);
    return 1.f / (1.f + __expf(-x));
}
__device__ __forceinline__ float tanhf_(float x) {
    x = fminf(fmaxf(x, -15.f), 15.f);
    float e = __expf(2.f * x);
    return (e - 1.f) / (e + 1.f);
}

// epoch-based group barrier; bar[0]=count, bar[1]=epoch; device scope.
__device__ __forceinline__ void group_barrier(unsigned* bar, unsigned target) {
    __threadfence();
    __syncthreads();
    if (threadIdx.x == 0) {
        unsigned prev = __hip_atomic_fetch_add(&bar[0], 1u, __ATOMIC_ACQ_REL, __HIP_MEMORY_SCOPE_AGENT);
        if (prev == WGS_PER_GROUP - 1) {
            __hip_atomic_store(&bar[0], 0u, __ATOMIC_RELAXED, __HIP_MEMORY_SCOPE_AGENT);
            __hip_atomic_store(&bar[1], target, __ATOMIC_RELEASE, __HIP_MEMORY_SCOPE_AGENT);
        } else {
            while (__hip_atomic_load(&bar[1], __ATOMIC_ACQUIRE, __HIP_MEMORY_SCOPE_AGENT) < target) {
                __builtin_amdgcn_s_sleep(1);
            }
        }
    }
    __syncthreads();
    __threadfence();
}

__global__ __launch_bounds__(256, 1) void lstm_persistent_kernel(
    const float* __restrict__ seq, const int* __restrict__ seq_len,
    const float* __restrict__ W_ih, const float* __restrict__ W_hh,
    const float* __restrict__ b_ih, const float* __restrict__ b_hh,
    float* __restrict__ out, char* __restrict__ ws)
{
    // LDS: act in A-fragment order (chunk c = kt*64+lane, 16B each) + gate regroup buffer
    __shared__ __align__(16) short act_lds[2048 * 8];     // 32 KB
    __shared__ float gates_lds[4][16][16];                 // 4 KB

    const int grp  = blockIdx.x & 3;        // group (XCD-locality swizzle)
    const int wg   = blockIdx.x >> 2;       // 0..63 within group
    const int s    = wg >> 5;               // stack 0/1
    const int u0   = (wg & 31) << 4;        // hidden-unit base (16 units per WG)
    const int bg   = grp << 4;              // batch base (16 rows per group)
    const int tid  = threadIdx.x;
    const int w    = tid >> 6;              // wave index == gate q (i,f,g,o)
    const int l    = tid & 63;
    const int quad = l >> 4;
    const int l15  = l & 15;
    const int cb   = tid >> 4;              // cell phase: batch 0..15
    const int cu   = tid & 15;              // cell phase: unit 0..15

    unsigned* bar = (unsigned*)(ws + grp * 256);
    short* h0b = (short*)(ws + 1024);                       // [2 par][64][512] bf16
    short* h1b = (short*)(ws + 1024 + 131072);
    short* ibb = (short*)(ws + 1024 + 2 * 131072);          // inp1 bf16
    float* ifb = (float*)(ws + 1024 + 3 * 131072);          // inp1 fp32

    // ---- persistent weights in VGPRs, pre-formatted as MFMA B-fragments ----
    // B-frag lane l holds W[row = q*512+u0+(l&15)][k = kt*32 + quad*8 + j]
    const float* Wi = W_ih + (size_t)s * 2048 * 512;
    const float* Wh = W_hh + (size_t)s * 2048 * 512;
    const int row = w * 512 + u0 + l15;
    v8s wf[32];
#pragma unroll
    for (int kt = 0; kt < 32; ++kt) {
        int ko = kt * 32 + quad * 8;
        const float* p = (ko < 512) ? (Wi + (size_t)row * 512 + ko)
                                    : (Wh + (size_t)row * 512 + (ko - 512));
        float4 x0 = *(const float4*)p;
        float4 x1 = *(const float4*)(p + 4);
        v8s v;
        v[0]=f2bf(x0.x); v[1]=f2bf(x0.y); v[2]=f2bf(x0.z); v[3]=f2bf(x0.w);
        v[4]=f2bf(x1.x); v[5]=f2bf(x1.y); v[6]=f2bf(x1.z); v[7]=f2bf(x1.w);
        wf[kt] = v;
    }

    float bias[4];
#pragma unroll
    for (int q = 0; q < 4; ++q)
        bias[q] = b_ih[s * 2048 + q * 512 + u0 + cu] + b_hh[s * 2048 + q * 512 + u0 + cu];

    const int len = seq_len[bg + cb];
    float hreg = 0.f, creg = 0.f;

    const short* myhb = (s == 0) ? h0b : h1b;

    // pipelined supersteps: stack0 computes t=tau, stack1 computes t=tau-1
    for (int tau = 0; tau <= TT; ++tau) {
        const int rp = tau & 1, wp = rp ^ 1;
        const int t  = (s == 0) ? tau : (tau - 1);
        const bool active = (s == 0) ? (tau < TT) : (tau >= 1);
        if (active) {
            // ---- stage act [16 x 1024] bf16 into LDS in A-fragment order ----
            const short* hsrc = myhb + rp * (64 * 512);
            const short* xsrc = ibb + rp * (64 * 512);
#pragma unroll
            for (int j = 0; j < 8; ++j) {
                int c  = (j << 8) + tid;
                int ll = c & 63;
                int m  = ll & 15;
                int ko = ((c >> 6) << 5) + ((ll >> 4) << 3);
                v8s v;
                if (ko < 512) {
                    if (s == 0) {
                        const float* p = seq + ((size_t)(bg + m) * TT + (size_t)t) * 512 + ko;
                        float4 x0 = *(const float4*)p;
                        float4 x1 = *(const float4*)(p + 4);
                        v[0]=f2bf(x0.x); v[1]=f2bf(x0.y); v[2]=f2bf(x0.z); v[3]=f2bf(x0.w);
                        v[4]=f2bf(x1.x); v[5]=f2bf(x1.y); v[6]=f2bf(x1.z); v[7]=f2bf(x1.w);
                    } else {
                        v = *(const v8s*)(xsrc + ((bg + m) << 9) + ko);
                    }
                } else {
                    v = *(const v8s*)(hsrc + ((bg + m) << 9) + (ko - 512));
                }
                *(v8s*)(act_lds + (size_t)c * 8) = v;
            }
            __syncthreads();

            // ---- MFMA: gates[16 batch x 16 units] for gate q=w, K=1024 ----
            v4f z = {0.f, 0.f, 0.f, 0.f};
            v4f acc[4] = {z, z, z, z};
#pragma unroll
            for (int kt = 0; kt < 32; ++kt) {
                v8s av = *(const v8s*)(act_lds + (kt * 64 + l) * 8);
                acc[kt & 3] = __builtin_amdgcn_mfma_f32_16x16x32_bf16(av, wf[kt], acc[kt & 3], 0, 0, 0);
            }
            v4f af = acc[0] + acc[1];
            af = af + acc[2];
            af = af + acc[3];
            // D layout: col(unit)=lane&15, row(batch)=quad*4+reg
#pragma unroll
            for (int r = 0; r < 4; ++r)
                gates_lds[w][quad * 4 + r][l15] = af[r];
            __syncthreads();

            // ---- cell update: thread owns (batch cb, unit cu) ----
            float gi = gates_lds[0][cb][cu] + bias[0];
            float gf = gates_lds[1][cb][cu] + bias[1];
            float gg = gates_lds[2][cb][cu] + bias[2];
            float go = gates_lds[3][cb][cu] + bias[3];
            float ii = sigmoidf_(gi), ff = sigmoidf_(gf);
            float gv = tanhf_(gg),   oo = sigmoidf_(go);
            float cs = ff * creg + ii * gv;
            float hs = oo * tanhf_(cs);
            const bool msk = (t < len);
            if (msk) { creg = cs; hreg = hs; }
            const int gidx = ((bg + cb) << 9) + u0 + cu;
            if (s == 0) {
                float x  = seq[((size_t)(bg + cb) * TT + (size_t)t) * 512 + u0 + cu];
                float i1 = hs + x;                       // residual (uses candidate hs, per ref)
                h0b[wp * (64 * 512) + gidx] = f2bf(hreg);
                ibb[wp * (64 * 512) + gidx] = f2bf(i1);
                ifb[wp * (64 * 512) + gidx] = i1;
            } else {
                float i1 = ifb[rp * (64 * 512) + gidx];
                out[((size_t)(bg + cb) * TT + (size_t)t) * 512 + u0 + cu] = msk ? (i1 + hs) : 0.f;
                h1b[wp * (64 * 512) + gidx] = f2bf(hreg);
            }
        }
        group_barrier(bar, (unsigned)(tau + 1));
    }

    // ---- final h, c ----
    const size_t OH = (size_t)BB * TT * HH;
    const size_t hoff = OH + (size_t)s * BB * HH + (size_t)(bg + cb) * HH + u0 + cu;
    out[hoff] = hreg;
    out[hoff + (size_t)2 * BB * HH] = creg;
}

extern "C" void kernel_launch(void* const* d_in, const int* in_sizes, int n_in,
                              void* d_out, int out_size, void* d_ws, size_t ws_size,
                              hipStream_t stream) {
    const float* seq     = (const float*)d_in[0];
    const int*   seq_len = (const int*)d_in[1];
    const float* W_ih    = (const float*)d_in[2];
    const float* W_hh    = (const float*)d_in[3];
    const float* b_ih    = (const float*)d_in[4];
    const float* b_hh    = (const float*)d_in[5];
    float* out = (float*)d_out;

    // ws: [0,1024) barriers; h0 2x64x512 bf16; h1; inp1 bf16; inp1 fp32
    const size_t ws_used = 1024 + 3 * 131072 + 262144;
    hipMemsetAsync(d_ws, 0, ws_used, stream);

    lstm_persistent_kernel<<<dim3(NGRP * WGS_PER_GROUP), dim3(256), 0, stream>>>(
        seq, seq_len, W_ih, W_hh, b_ih, b_hh, out, (char*)d_ws);
}

// Round 4
// 4869.213 us; speedup vs baseline: 10.9831x; 10.9831x over previous
//
#include <hip/hip_runtime.h>
#include <stdint.h>

#define BB 64
#define TT 1024
#define HH 512
typedef unsigned long long ull;
typedef float v4f __attribute__((ext_vector_type(4)));
typedef short v8s __attribute__((ext_vector_type(8)));

__device__ __forceinline__ short f2bf(float f) {
    unsigned u = __float_as_uint(f);
    u += 0x7fffu + ((u >> 16) & 1u);          // RNE to bf16
    return (short)(u >> 16);
}
__device__ __forceinline__ float sigmoidf_(float x) {
    x = fminf(fmaxf(x, -30.f), 30.f);
    return 1.f / (1.f + __expf(-x));
}
__device__ __forceinline__ float tanhf_(float x) {
    x = fminf(fmaxf(x, -15.f), 15.f);
    float e = __expf(2.f * x);
    return (e - 1.f) / (e + 1.f);
}

// Relaxed agent-scope ops: lower to sc0/sc1-flagged global ops (bypass L1/L2,
// served at the device coherence point). NO buffer_wbl2 / buffer_inv emitted.
__device__ __forceinline__ ull aload64(const ull* p) {
    return __hip_atomic_load(p, __ATOMIC_RELAXED, __HIP_MEMORY_SCOPE_AGENT);
}
__device__ __forceinline__ void astore64(ull* p, ull v) {
    __hip_atomic_store(p, v, __ATOMIC_RELAXED, __HIP_MEMORY_SCOPE_AGENT);
}
__device__ __forceinline__ float aloadf(const float* p) {
    return __hip_atomic_load(p, __ATOMIC_RELAXED, __HIP_MEMORY_SCOPE_AGENT);
}
__device__ __forceinline__ void wait_ge(unsigned* c, unsigned tgt) {
    while (__hip_atomic_load(c, __ATOMIC_RELAXED, __HIP_MEMORY_SCOPE_AGENT) < tgt)
        __builtin_amdgcn_s_sleep(1);
}

// Grid: 128 WGs x 512 threads. WG = (batch-group g in [0,4), stack s, 32 hidden units).
// Sync-group = (g, s): 16 WGs, coupled via monotonic counter cnt[g][s].
// Buffers 4-deep; stack1 trails stack0 by one superstep (software pipeline).
__global__ __launch_bounds__(512, 2) void lstm_persistent_kernel(
    const float* __restrict__ seq, const int* __restrict__ seq_len,
    const float* __restrict__ W_ih, const float* __restrict__ W_hh,
    const float* __restrict__ b_ih, const float* __restrict__ b_hh,
    float* __restrict__ out, char* __restrict__ ws)
{
    __shared__ __align__(16) short act_lds[2048 * 8];   // 32 KB, A-frag order
    __shared__ float gates_lds[4][16][32];              // 8 KB
    __shared__ __align__(8) short hstore[16][32];
    __shared__ __align__(8) short istore[16][32];
    __shared__ __align__(8) float fstore[16][32];

    const int gid = blockIdx.x;
    const int g   = gid & 3;
    const int s   = (gid >> 2) & 1;
    const int u0  = (gid >> 3) << 5;     // 32-unit base
    const int bg  = g << 4;
    const int tid = threadIdx.x;
    const int w   = tid >> 6;            // wave 0..7
    const int l   = tid & 63;
    const int q   = w >> 1;              // gate i,f,g,o
    const int uh  = w & 1;               // unit half
    const int quad = l >> 4, l15 = l & 15;
    const int cb  = tid >> 5, cu = tid & 31;   // cell phase: batch, unit

    unsigned* cnt0 = (unsigned*)ws + g * 64;   // 256 B apart per group
    unsigned* cnt1 = cnt0 + 32;
    short* h0b = (short*)(ws + 1024);                  // [4 slot][4 grp][16][512] bf16
    short* h1b = h0b + 4 * 4 * 16 * 512;
    short* ib  = h1b + 4 * 4 * 16 * 512;               // inp1 bf16
    float* ifb = (float*)(ib + 4 * 4 * 16 * 512);      // inp1 fp32

    // ---- persistent weights in VGPRs as MFMA B-fragments ----
    const float* Wi = W_ih + (size_t)s * (2048 * 512);
    const float* Wh = W_hh + (size_t)s * (2048 * 512);
    const int row = q * 512 + u0 + uh * 16 + l15;
    v8s wf[32];
#pragma unroll
    for (int kt = 0; kt < 32; ++kt) {
        int ko = kt * 32 + quad * 8;
        const float* p = (ko < 512) ? (Wi + (size_t)row * 512 + ko)
                                    : (Wh + (size_t)row * 512 + (ko - 512));
        float4 x0 = *(const float4*)p;
        float4 x1 = *(const float4*)(p + 4);
        v8s v;
        v[0]=f2bf(x0.x); v[1]=f2bf(x0.y); v[2]=f2bf(x0.z); v[3]=f2bf(x0.w);
        v[4]=f2bf(x1.x); v[5]=f2bf(x1.y); v[6]=f2bf(x1.z); v[7]=f2bf(x1.w);
        wf[kt] = v;
    }
    float bias[4];
#pragma unroll
    for (int qq = 0; qq < 4; ++qq)
        bias[qq] = b_ih[s * 2048 + qq * 512 + u0 + cu] + b_hh[s * 2048 + qq * 512 + u0 + cu];
    const int len = seq_len[bg + cb];
    float hreg = 0.f, creg = 0.f;
    short* myhb = (s == 0) ? h0b : h1b;

    for (int tau = 0; tau <= TT; ++tau) {
        if (s == 0 && tau >= TT) break;
        if (s == 1 && tau == 0) continue;
        const int t   = (s == 0) ? tau : tau - 1;
        const int rsl = (tau - 1) & 3;
        const int wsl = tau & 3;
        float xres = 0.f;

        if (s == 0) {
            // x-part staging from seq (no cross-WG dependency) BEFORE the wait
#pragma unroll
            for (int j = 0; j < 2; ++j) {
                int c = (j << 9) + tid;
                int ll = c & 63, m = ll & 15;
                int ko = ((c >> 6) << 5) + ((ll >> 4) << 3);
                const float* p = seq + (((size_t)(bg + m) * TT + t) << 9) + ko;
                float4 x0 = *(const float4*)p, x1 = *(const float4*)(p + 4);
                v8s v;
                v[0]=f2bf(x0.x); v[1]=f2bf(x0.y); v[2]=f2bf(x0.z); v[3]=f2bf(x0.w);
                v[4]=f2bf(x1.x); v[5]=f2bf(x1.y); v[6]=f2bf(x1.z); v[7]=f2bf(x1.w);
                *(v8s*)(act_lds + (size_t)c * 8) = v;
            }
            xres = seq[(((size_t)(bg + cb) * TT + t) << 9) + u0 + cu];
            if (tid == 0) {
                if (tau >= 1) wait_ge(cnt0, 16u * tau);         // own allgather
                if (tau >= 3) wait_ge(cnt1, 16u * (tau - 2));   // anti-dep (slot reuse)
            }
        } else {
            if (tid == 0) {
                wait_ge(cnt0, 16u * tau);                        // inp1 ready
                if (tau >= 2) wait_ge(cnt1, 16u * (tau - 1));    // own allgather (FIX: was 16*tau -> deadlock)
            }
        }
        __syncthreads();   // release whole WG after tid0's waits

        if (s == 1) {
            // x-part = inp1 bf16 from stack0 (slot rsl)
#pragma unroll
            for (int j = 0; j < 2; ++j) {
                int c = (j << 9) + tid;
                int ll = c & 63, m = ll & 15;
                int ko = ((c >> 6) << 5) + ((ll >> 4) << 3);
                const ull* p = (const ull*)(ib + (((((rsl << 2) | g) << 4) + m) << 9) + ko);
                ull a = aload64(p), b = aload64(p + 1);
                *(ull*)(act_lds + (size_t)c * 8) = a;
                *((ull*)(act_lds + (size_t)c * 8) + 1) = b;
            }
        }
        // h-part (chunks c in [1024,2048))
        if (tau == (s == 0 ? 0 : 1)) {
#pragma unroll
            for (int j = 2; j < 4; ++j) {
                int c = (j << 9) + tid;
                *(ull*)(act_lds + (size_t)c * 8) = 0ull;
                *((ull*)(act_lds + (size_t)c * 8) + 1) = 0ull;
            }
        } else {
#pragma unroll
            for (int j = 2; j < 4; ++j) {
                int c = (j << 9) + tid;
                int ll = c & 63, m = ll & 15;
                int ko = ((c >> 6) << 5) + ((ll >> 4) << 3) - 512;
                const ull* p = (const ull*)(myhb + (((((rsl << 2) | g) << 4) + m) << 9) + ko);
                ull a = aload64(p), b = aload64(p + 1);
                *(ull*)(act_lds + (size_t)c * 8) = a;
                *((ull*)(act_lds + (size_t)c * 8) + 1) = b;
            }
        }
        __syncthreads();

        // ---- MFMA: gates[16 batch x 16 units] per wave, K=1024 ----
        v4f z = {0.f, 0.f, 0.f, 0.f};
        v4f acc0 = z, acc1 = z, acc2 = z, acc3 = z;
#pragma unroll
        for (int kt = 0; kt < 32; kt += 4) {
            v8s a0 = *(const v8s*)(act_lds + ((kt + 0) * 64 + l) * 8);
            v8s a1 = *(const v8s*)(act_lds + ((kt + 1) * 64 + l) * 8);
            v8s a2 = *(const v8s*)(act_lds + ((kt + 2) * 64 + l) * 8);
            v8s a3 = *(const v8s*)(act_lds + ((kt + 3) * 64 + l) * 8);
            acc0 = __builtin_amdgcn_mfma_f32_16x16x32_bf16(a0, wf[kt + 0], acc0, 0, 0, 0);
            acc1 = __builtin_amdgcn_mfma_f32_16x16x32_bf16(a1, wf[kt + 1], acc1, 0, 0, 0);
            acc2 = __builtin_amdgcn_mfma_f32_16x16x32_bf16(a2, wf[kt + 2], acc2, 0, 0, 0);
            acc3 = __builtin_amdgcn_mfma_f32_16x16x32_bf16(a3, wf[kt + 3], acc3, 0, 0, 0);
        }
        v4f af = (acc0 + acc1) + (acc2 + acc3);
#pragma unroll
        for (int r = 0; r < 4; ++r)
            gates_lds[q][quad * 4 + r][uh * 16 + l15] = af[r];
        __syncthreads();

        // ---- cell update: thread owns (batch cb, unit cu) ----
        float gi = gates_lds[0][cb][cu] + bias[0];
        float gf = gates_lds[1][cb][cu] + bias[1];
        float gg = gates_lds[2][cb][cu] + bias[2];
        float go = gates_lds[3][cb][cu] + bias[3];
        float ii = sigmoidf_(gi), ff = sigmoidf_(gf);
        float gv = tanhf_(gg),   oo = sigmoidf_(go);
        float cs = ff * creg + ii * gv;
        float hs = oo * tanhf_(cs);
        const bool msk = (t < len);
        if (msk) { creg = cs; hreg = hs; }
        if (s == 0) {
            float i1 = hs + xres;                       // candidate residual, per ref
            hstore[cb][cu] = f2bf(hreg);
            istore[cb][cu] = f2bf(i1);
            fstore[cb][cu] = i1;
        } else {
            float i1 = aloadf(ifb + (((((rsl << 2) | g) << 4) + cb) << 9) + u0 + cu);
            out[(((size_t)(bg + cb) * TT + t) << 9) + u0 + cu] = msk ? (i1 + hs) : 0.f;
            hstore[cb][cu] = f2bf(hreg);
        }
        __syncthreads();

        // ---- scatter to coherence point (8 B flagged stores) ----
        const int base = (((wsl << 2) | g) << 4);
        if (s == 0) {
            if (tid < 128) {
                int r = tid >> 3, o = (tid & 7) << 2;
                astore64((ull*)(h0b + ((base + r) << 9) + u0 + o), *(const ull*)&hstore[r][o]);
            } else if (tid < 256) {
                int t2 = tid - 128; int r = t2 >> 3, o = (t2 & 7) << 2;
                astore64((ull*)(ib + ((base + r) << 9) + u0 + o), *(const ull*)&istore[r][o]);
            } else {
                int t2 = tid - 256; int r = t2 >> 4, o = (t2 & 15) << 1;
                astore64((ull*)(ifb + ((base + r) << 9) + u0 + o), *(const ull*)&fstore[r][o]);
            }
        } else {
            if (tid < 128) {
                int r = tid >> 3, o = (tid & 7) << 2;
                astore64((ull*)(h1b + ((base + r) << 9) + u0 + o), *(const ull*)&hstore[r][o]);
            }
        }
        asm volatile("s_waitcnt vmcnt(0)" ::: "memory");
        __syncthreads();
        if (tid == 0)
            __hip_atomic_fetch_add((s == 0) ? cnt0 : cnt1, 1u,
                                   __ATOMIC_RELAXED, __HIP_MEMORY_SCOPE_AGENT);
    }

    // ---- final h, c ----
    const size_t OH = (size_t)BB * TT * HH;
    const size_t hoff = OH + (size_t)s * BB * HH + ((size_t)(bg + cb) << 9) + u0 + cu;
    out[hoff] = hreg;
    out[hoff + (size_t)2 * BB * HH] = creg;
}

extern "C" void kernel_launch(void* const* d_in, const int* in_sizes, int n_in,
                              void* d_out, int out_size, void* d_ws, size_t ws_size,
                              hipStream_t stream) {
    const float* seq     = (const float*)d_in[0];
    const int*   seq_len = (const int*)d_in[1];
    const float* W_ih    = (const float*)d_in[2];
    const float* W_hh    = (const float*)d_in[3];
    const float* b_ih    = (const float*)d_in[4];
    const float* b_hh    = (const float*)d_in[5];
    float* out = (float*)d_out;

    hipMemsetAsync(d_ws, 0, 1024, stream);   // counters only; buffers never read stale

    lstm_persistent_kernel<<<dim3(128), dim3(512), 0, stream>>>(
        seq, seq_len, W_ih, W_hh, b_ih, b_hh, out, (char*)d_ws);
}

// Round 5
// 4089.523 us; speedup vs baseline: 13.0771x; 1.1907x over previous
//
#include <hip/hip_runtime.h>
#include <stdint.h>

#define BB 64
#define TT 1024
#define HH 512
typedef unsigned long long ull;
typedef float v4f __attribute__((ext_vector_type(4)));
typedef short v8s __attribute__((ext_vector_type(8)));
typedef unsigned v4u __attribute__((ext_vector_type(4)));

__device__ __forceinline__ short f2bf(float f) {
    unsigned u = __float_as_uint(f);
    u += 0x7fffu + ((u >> 16) & 1u);          // RNE to bf16
    return (short)(u >> 16);
}
__device__ __forceinline__ float sigmoidf_(float x) {
    x = fminf(fmaxf(x, -30.f), 30.f);
    return 1.f / (1.f + __expf(-x));
}
__device__ __forceinline__ float tanhf_(float x) {
    x = fminf(fmaxf(x, -15.f), 15.f);
    float e = __expf(2.f * x);
    return (e - 1.f) / (e + 1.f);
}

__device__ __forceinline__ unsigned aload32(const unsigned* p) {
    return __hip_atomic_load(p, __ATOMIC_RELAXED, __HIP_MEMORY_SCOPE_AGENT);
}
__device__ __forceinline__ void wait_ge(unsigned* c, unsigned tgt) {
    while (__hip_atomic_load(c, __ATOMIC_RELAXED, __HIP_MEMORY_SCOPE_AGENT) < tgt)
        __builtin_amdgcn_s_sleep(1);
}
// fire-and-forget tagged store to the device coherence point (no L1/L2 hit)
__device__ __forceinline__ void stcc(unsigned* p, unsigned v) {
    asm volatile("global_store_dword %0, %1, off sc0 sc1" :: "v"(p), "v"(v) : "memory");
}
// 2 chunks (rows m, m+1 at same k): 4 dwordx4 coherent loads, all in flight, one wait
__device__ __forceinline__ void ld4cc(const unsigned* p, v4u& r0, v4u& r1, v4u& r2, v4u& r3) {
    asm volatile(
        "global_load_dwordx4 %0, %4, off sc0 sc1\n\t"
        "global_load_dwordx4 %1, %4, off offset:16 sc0 sc1\n\t"
        "global_load_dwordx4 %2, %4, off offset:2048 sc0 sc1\n\t"
        "global_load_dwordx4 %3, %4, off offset:2064 sc0 sc1\n\t"
        "s_waitcnt vmcnt(0)"
        : "=&v"(r0), "=&v"(r1), "=&v"(r2), "=&v"(r3)
        : "v"(p) : "memory");
}
// 4 chunks from two bases (x-part and h-part), 8 loads in flight, one wait
__device__ __forceinline__ void ld8cc(const unsigned* px, const unsigned* ph,
        v4u& x0, v4u& x1, v4u& x2, v4u& x3, v4u& h0, v4u& h1, v4u& h2, v4u& h3) {
    asm volatile(
        "global_load_dwordx4 %0, %8, off sc0 sc1\n\t"
        "global_load_dwordx4 %1, %8, off offset:16 sc0 sc1\n\t"
        "global_load_dwordx4 %2, %8, off offset:2048 sc0 sc1\n\t"
        "global_load_dwordx4 %3, %8, off offset:2064 sc0 sc1\n\t"
        "global_load_dwordx4 %4, %9, off sc0 sc1\n\t"
        "global_load_dwordx4 %5, %9, off offset:16 sc0 sc1\n\t"
        "global_load_dwordx4 %6, %9, off offset:2048 sc0 sc1\n\t"
        "global_load_dwordx4 %7, %9, off offset:2064 sc0 sc1\n\t"
        "s_waitcnt vmcnt(0)"
        : "=&v"(x0), "=&v"(x1), "=&v"(x2), "=&v"(x3),
          "=&v"(h0), "=&v"(h1), "=&v"(h2), "=&v"(h3)
        : "v"(px), "v"(ph) : "memory");
}
__device__ __forceinline__ unsigned tagdiff(v4u a, v4u b, unsigned tg) {
    return ((a.x ^ tg) | (a.y ^ tg) | (a.z ^ tg) | (a.w ^ tg) |
            (b.x ^ tg) | (b.y ^ tg) | (b.z ^ tg) | (b.w ^ tg)) & 0xFFFFu;
}
__device__ __forceinline__ void packlds(short* dst, v4u a, v4u b) {
    v4u d;
    d.x = (a.x >> 16) | (a.y & 0xFFFF0000u);
    d.y = (a.z >> 16) | (a.w & 0xFFFF0000u);
    d.z = (b.x >> 16) | (b.y & 0xFFFF0000u);
    d.w = (b.z >> 16) | (b.w & 0xFFFF0000u);
    *(v4u*)dst = d;
}

// Grid: 128 WGs x 512 threads. WG = (batch-group g, stack s, 32-unit tile).
// Cross-WG sync: tag-in-data polling only; rc1 counter = off-path ib anti-dep.
__global__ __launch_bounds__(512, 1) void lstm_persistent_kernel(
    const float* __restrict__ seq, const int* __restrict__ seq_len,
    const float* __restrict__ W_ih, const float* __restrict__ W_hh,
    const float* __restrict__ b_ih, const float* __restrict__ b_hh,
    float* __restrict__ out, char* __restrict__ ws)
{
    __shared__ __align__(16) short act_lds[2048 * 8];   // 32 KB, A-frag order
    __shared__ float gates_lds[4][16][32];              // 8 KB

    const int gid = blockIdx.x;
    const int g   = gid & 3;
    const int s   = (gid >> 2) & 1;
    const int u0  = (gid >> 3) << 5;
    const int bg  = g << 4;
    const int tid = threadIdx.x;
    const int w   = tid >> 6;
    const int l   = tid & 63;
    const int q   = w >> 1;
    const int uh  = w & 1;
    const int quad = l >> 4, l15 = l & 15;
    const int cb  = tid >> 5, cu = tid & 31;

    unsigned* rc1 = (unsigned*)(ws + g * 256);
    unsigned* h0b = (unsigned*)(ws + 1024);            // [4 slot][4 grp][16][512] tagged u32
    unsigned* h1b = h0b + 4 * 4 * 16 * 512;
    unsigned* ibb = h1b + 4 * 4 * 16 * 512;

    // ---- persistent weights in VGPRs as MFMA B-fragments ----
    const float* Wi = W_ih + (size_t)s * (2048 * 512);
    const float* Wh = W_hh + (size_t)s * (2048 * 512);
    const int row = q * 512 + u0 + uh * 16 + l15;
    v8s wf[32];
#pragma unroll
    for (int kt = 0; kt < 32; ++kt) {
        int ko = kt * 32 + quad * 8;
        const float* p = (ko < 512) ? (Wi + (size_t)row * 512 + ko)
                                    : (Wh + (size_t)row * 512 + (ko - 512));
        float4 x0 = *(const float4*)p;
        float4 x1 = *(const float4*)(p + 4);
        v8s v;
        v[0]=f2bf(x0.x); v[1]=f2bf(x0.y); v[2]=f2bf(x0.z); v[3]=f2bf(x0.w);
        v[4]=f2bf(x1.x); v[5]=f2bf(x1.y); v[6]=f2bf(x1.z); v[7]=f2bf(x1.w);
        wf[kt] = v;
    }
    float bias[4];
#pragma unroll
    for (int qq = 0; qq < 4; ++qq)
        bias[qq] = b_ih[s * 2048 + qq * 512 + u0 + cu] + b_hh[s * 2048 + qq * 512 + u0 + cu];
    const int len = seq_len[bg + cb];
    float hreg = 0.f, creg = 0.f;

    // per-thread chunk geometry (chunk pairs: rows m0,m0+1 at same k-offset)
    const int ch0 = 1024 + (tid << 1);                 // h-part chunk
    const int mh  = ch0 & 15;
    const int kh  = (((ch0 >> 6) << 5) + (((ch0 >> 4) & 3) << 3)) - 512;
    const int cx0 = tid << 1;                          // x-part chunk (s1)
    const int mx  = cx0 & 15;
    const int kx  = ((cx0 >> 6) << 5) + (((cx0 >> 4) & 3) << 3);
    unsigned* myhb = (s == 0) ? h0b : h1b;

    for (int tau = 0; tau <= TT; ++tau) {
        if (s == 0 && tau >= TT) break;
        if (s == 1 && tau == 0) continue;
        const int t   = (s == 0) ? tau : tau - 1;
        const int rb  = (((tau - 1) & 3) << 2 | g) << 13;   // read slot base (u32 idx)
        const int wb  = ((tau & 3) << 2 | g) << 13;         // write slot base
        const unsigned tg = (unsigned)(tau - 1);
        float xres = 0.f;
        unsigned rcv = 0xFFFFFFFFu;

        if (s == 0) {
            if (tid == 0 && tau >= 4) rcv = aload32(rc1);   // preload anti-dep hint
            // x-part from seq (plain loads, no cross-WG dep)
#pragma unroll
            for (int j = 0; j < 2; ++j) {
                int c = (j << 9) + tid;
                int ll = c & 63, m = ll & 15;
                int ko = ((c >> 6) << 5) + ((ll >> 4) << 3);
                const float* p = seq + (((size_t)(bg + m) * TT + t) << 9) + ko;
                float4 x0 = *(const float4*)p, x1 = *(const float4*)(p + 4);
                v8s v;
                v[0]=f2bf(x0.x); v[1]=f2bf(x0.y); v[2]=f2bf(x0.z); v[3]=f2bf(x0.w);
                v[4]=f2bf(x1.x); v[5]=f2bf(x1.y); v[6]=f2bf(x1.z); v[7]=f2bf(x1.w);
                *(v8s*)(act_lds + (size_t)c * 8) = v;
            }
            xres = seq[(((size_t)(bg + cb) * TT + t) << 9) + u0 + cu];
            // h-part: poll own-group tagged data
            if (tau == 0) {
                v4u zz = {0, 0, 0, 0};
                *(v4u*)(act_lds + (size_t)ch0 * 8) = zz;
                *(v4u*)(act_lds + (size_t)(ch0 + 1) * 8) = zz;
            } else {
                const unsigned* hp = h0b + rb + (mh << 9) + kh;
                for (;;) {
                    v4u r0, r1, r2, r3;
                    ld4cc(hp, r0, r1, r2, r3);
                    if ((tagdiff(r0, r1, tg) | tagdiff(r2, r3, tg)) == 0) {
                        packlds(act_lds + (size_t)ch0 * 8, r0, r1);
                        packlds(act_lds + (size_t)(ch0 + 1) * 8, r2, r3);
                        break;
                    }
                }
            }
        } else {
            const unsigned* px = ibb + rb + (mx << 9) + kx;
            if (tau == 1) {
                v4u zz = {0, 0, 0, 0};
                *(v4u*)(act_lds + (size_t)ch0 * 8) = zz;
                *(v4u*)(act_lds + (size_t)(ch0 + 1) * 8) = zz;
                for (;;) {
                    v4u r0, r1, r2, r3;
                    ld4cc(px, r0, r1, r2, r3);
                    if ((tagdiff(r0, r1, tg) | tagdiff(r2, r3, tg)) == 0) {
                        packlds(act_lds + (size_t)cx0 * 8, r0, r1);
                        packlds(act_lds + (size_t)(cx0 + 1) * 8, r2, r3);
                        break;
                    }
                }
            } else {
                const unsigned* ph = h1b + rb + (mh << 9) + kh;
                for (;;) {
                    v4u x0, x1, x2, x3, h0, h1, h2, h3;
                    ld8cc(px, ph, x0, x1, x2, x3, h0, h1, h2, h3);
                    if ((tagdiff(x0, x1, tg) | tagdiff(x2, x3, tg) |
                         tagdiff(h0, h1, tg) | tagdiff(h2, h3, tg)) == 0) {
                        packlds(act_lds + (size_t)cx0 * 8, x0, x1);
                        packlds(act_lds + (size_t)(cx0 + 1) * 8, x2, x3);
                        packlds(act_lds + (size_t)ch0 * 8, h0, h1);
                        packlds(act_lds + (size_t)(ch0 + 1) * 8, h2, h3);
                        break;
                    }
                }
            }
        }
        __syncthreads();
        if (s == 1 && tid == 0)      // staging done: release ib slot (off-path)
            __hip_atomic_fetch_add(rc1, 1u, __ATOMIC_RELAXED, __HIP_MEMORY_SCOPE_AGENT);

        // ---- MFMA: gates[16 batch x 16 units] per wave, K=1024 ----
        v4f z = {0.f, 0.f, 0.f, 0.f};
        v4f acc0 = z, acc1 = z, acc2 = z, acc3 = z;
#pragma unroll
        for (int kt = 0; kt < 32; kt += 4) {
            v8s a0 = *(const v8s*)(act_lds + ((kt + 0) * 64 + l) * 8);
            v8s a1 = *(const v8s*)(act_lds + ((kt + 1) * 64 + l) * 8);
            v8s a2 = *(const v8s*)(act_lds + ((kt + 2) * 64 + l) * 8);
            v8s a3 = *(const v8s*)(act_lds + ((kt + 3) * 64 + l) * 8);
            acc0 = __builtin_amdgcn_mfma_f32_16x16x32_bf16(a0, wf[kt + 0], acc0, 0, 0, 0);
            acc1 = __builtin_amdgcn_mfma_f32_16x16x32_bf16(a1, wf[kt + 1], acc1, 0, 0, 0);
            acc2 = __builtin_amdgcn_mfma_f32_16x16x32_bf16(a2, wf[kt + 2], acc2, 0, 0, 0);
            acc3 = __builtin_amdgcn_mfma_f32_16x16x32_bf16(a3, wf[kt + 3], acc3, 0, 0, 0);
        }
        v4f af = (acc0 + acc1) + (acc2 + acc3);
#pragma unroll
        for (int r = 0; r < 4; ++r)
            gates_lds[q][quad * 4 + r][uh * 16 + l15] = af[r];
        __syncthreads();

        // ---- cell update: thread owns (batch cb, unit cu) ----
        float gi = gates_lds[0][cb][cu] + bias[0];
        float gf = gates_lds[1][cb][cu] + bias[1];
        float gg = gates_lds[2][cb][cu] + bias[2];
        float go = gates_lds[3][cb][cu] + bias[3];
        float ii = sigmoidf_(gi), ff = sigmoidf_(gf);
        float gv = tanhf_(gg),   oo = sigmoidf_(go);
        float cs = ff * creg + ii * gv;
        float hs = oo * tanhf_(cs);
        const bool msk = (t < len);
        if (msk) { creg = cs; hreg = hs; }
        float i1s = 0.f;
        if (s == 0) {
            i1s = hs + xres;                            // candidate residual, per ref
        } else {
            int k  = u0 + cu;                           // staged bf16 i1 from LDS
            int cI = ((k >> 5) << 6) + (((k >> 3) & 3) << 4) + cb;
            unsigned short us = (unsigned short)act_lds[cI * 8 + (k & 7)];
            float i1 = __uint_as_float(((unsigned)us) << 16);
            out[(((size_t)(bg + cb) * TT + t) << 9) + u0 + cu] = msk ? (i1 + hs) : 0.f;
        }
        if (s == 0 && tid == 0 && tau >= 4) {           // ib slot anti-dep (usually free)
            unsigned need = 16u * (unsigned)(tau - 3);
            if (rcv < need) wait_ge(rc1, need);
        }
        __syncthreads();   // gate stores on anti-dep; also protects act_lds/gates_lds reuse

        // ---- tagged scatter to coherence point (fire-and-forget) ----
        const unsigned otg = (unsigned)tau;
        const int widx = wb + (cb << 9) + u0 + cu;
        if (s == 0) {
            stcc(h0b + widx, (((unsigned)(unsigned short)f2bf(hreg)) << 16) | otg);
            stcc(ibb + widx, (((unsigned)(unsigned short)f2bf(i1s)) << 16) | otg);
        } else {
            stcc(h1b + widx, (((unsigned)(unsigned short)f2bf(hreg)) << 16) | otg);
        }
    }

    // ---- final h, c ----
    const size_t OH = (size_t)BB * TT * HH;
    const size_t hoff = OH + (size_t)s * BB * HH + ((size_t)(bg + cb) << 9) + u0 + cu;
    out[hoff] = hreg;
    out[hoff + (size_t)2 * BB * HH] = creg;
}

extern "C" void kernel_launch(void* const* d_in, const int* in_sizes, int n_in,
                              void* d_out, int out_size, void* d_ws, size_t ws_size,
                              hipStream_t stream) {
    const float* seq     = (const float*)d_in[0];
    const int*   seq_len = (const int*)d_in[1];
    const float* W_ih    = (const float*)d_in[2];
    const float* W_hh    = (const float*)d_in[3];
    const float* b_ih    = (const float*)d_in[4];
    const float* b_hh    = (const float*)d_in[5];
    float* out = (float*)d_out;

    hipMemsetAsync(d_ws, 0, 1024, stream);   // rc1 counters; data buffers are tag-guarded

    lstm_persistent_kernel<<<dim3(128), dim3(512), 0, stream>>>(
        seq, seq_len, W_ih, W_hh, b_ih, b_hh, out, (char*)d_ws);
}